// Round 26
// baseline (45.893 us; speedup 1.0000x reference)
//
#include <hip/hip_runtime.h>
#include <math.h>

#define C2 2.8853900817779268f   // 2*log2(e)

typedef __attribute__((address_space(3))) unsigned int       lds_u32;
typedef const __attribute__((address_space(1))) unsigned int g_u32;

__device__ __forceinline__ void stage16(const float* g, float* l) {
    __builtin_amdgcn_global_load_lds((g_u32*)g, (lds_u32*)l, 16, 0, 0);
}

// ---------------- score kernel ----------------
// 512 blocks x 512 thr; block = (b, k-half, 32-row-group); 80 KB LDS ->
// 2 blocks/CU = 4 waves/SIMD. Phase-homogeneous. w is read via VMEM
// (lane-blinded pointer -> global_load on vmcnt, L1-hot single line) so the
// g-loop has NO SMEM: ds_read waits (lgkmcnt) never serialize on w (r14 bug).
__global__ __launch_bounds__(512, 4) void score_kernel(
    const float* __restrict__ q_g, const float* __restrict__ k_g,
    const float* __restrict__ w_g, float* __restrict__ sc_ws)
{
    __shared__ float kbuf[16384];   // 64 KB: Ek[t2][g32][rot64][hi4]
    __shared__ float sEq[4096];     // 16 KB: 8 waves x Eq[4][128]

    const int tid  = threadIdx.x;
    const int lane = tid & 63;
    const int wv   = __builtin_amdgcn_readfirstlane(tid >> 6);  // 0..7

    const int xcd = blockIdx.x & 7;
    const int sub = blockIdx.x >> 3;          // 0..63
    const int b   = (xcd << 2) + (sub >> 4);  // 4 batches per XCD
    const int rem = sub & 15;
    const int kh  = rem >> 3;                 // k-half
    const int rg  = rem & 7;                  // row-group
    const int qr0 = (rg << 5) + (wv << 2);    // wave's 4 q rows

    float* strip = sEq + (wv << 9);           // Eq[4][128], wave-private

    // Eq = exp2(C2*q) for the wave's 4 rows
    {
        const float* qb = q_g + (size_t)(b * 256 + qr0) * 128;
        #pragma unroll
        for (int j = 0; j < 2; ++j) {
            int f = lane + (j << 6);
            int r = f >> 5, c = f & 31;
            float4 qv = *(const float4*)(qb + (r << 7) + (c << 2));
            float4 E;
            E.x = __builtin_amdgcn_exp2f(C2 * qv.x);
            E.y = __builtin_amdgcn_exp2f(C2 * qv.y);
            E.z = __builtin_amdgcn_exp2f(C2 * qv.z);
            E.w = __builtin_amdgcn_exp2f(C2 * qv.w);
            *(float4*)&strip[(r << 7) + (c << 2)] = E;
        }
    }

    // stage K rows [kh*128, +128): load -> exp2 -> rotation-swizzled kbuf
    {
        const float4* kg4 = (const float4*)(k_g + (size_t)b * 32768 + (kh << 14));
        #pragma unroll
        for (int j = 0; j < 8; ++j) {
            int f = tid + (j << 9);            // 0..4095 float4s
            float4 kv = kg4[f];
            int k = f >> 5, g = f & 31;        // k 0..127, g 0..31
            float4 E;
            E.x = __builtin_amdgcn_exp2f(C2 * kv.x);
            E.y = __builtin_amdgcn_exp2f(C2 * kv.y);
            E.z = __builtin_amdgcn_exp2f(C2 * kv.z);
            E.w = __builtin_amdgcn_exp2f(C2 * kv.w);
            int rot = ((k & 63) + g) & 63;
            *(float4*)&kbuf[((k >> 6) << 13) + (g << 8) + (rot << 2)] = E;
        }
    }

    // blind w pointer into VGPRs: forces VMEM loads (vmcnt), not s_load (lgkmcnt)
    const float* wp = w_g;
    asm volatile("" : "+v"(wp));

    __syncthreads();    // the only barrier

    // score: g outer; 8 accumulators [t2][r4]; loop has only ds_read + 1 VMEM
    float s[2][4];
    #pragma unroll
    for (int t = 0; t < 2; ++t)
        #pragma unroll
        for (int r = 0; r < 4; ++r) s[t][r] = 0.f;

    #pragma unroll 4
    for (int g = 0; g < 32; ++g) {
        float4 w4 = *(const float4*)(wp + (g << 2));          // VMEM, L1-hot line
        float4 e0 = *(const float4*)&strip[g << 2];
        float4 e1 = *(const float4*)&strip[128 + (g << 2)];
        float4 e2 = *(const float4*)&strip[256 + (g << 2)];
        float4 e3 = *(const float4*)&strip[384 + (g << 2)];
        const int rot = (((lane + g) & 63) << 2) + (g << 8);
        #pragma unroll
        for (int t = 0; t < 2; ++t) {
            float4 k4 = *(const float4*)&kbuf[(t << 13) + rot];
            #define RB(E, S)                                                   \
            {                                                                  \
                float d0 = fmaf(E.x, k4.x, 1.f), d1 = fmaf(E.y, k4.y, 1.f);    \
                float d2 = fmaf(E.z, k4.z, 1.f), d3 = fmaf(E.w, k4.w, 1.f);    \
                float P01 = d0 * d1, P23 = d2 * d3;                            \
                float N01 = fmaf(w4.x, d1, w4.y * d0);                         \
                float N23 = fmaf(w4.z, d3, w4.w * d2);                         \
                float num = fmaf(N01, P23, N23 * P01);                         \
                S = fmaf(num, __builtin_amdgcn_rcpf(P01 * P23), S);            \
            }
            RB(e0, s[t][0])
            RB(e1, s[t][1])
            RB(e2, s[t][2])
            RB(e3, s[t][3])
            #undef RB
        }
    }

    // write scores (pre-scaled by -C2); lane = k within tile, coalesced
    #pragma unroll
    for (int r = 0; r < 4; ++r) {
        float* br = sc_ws + (size_t)(b * 256 + qr0 + r) * 256 + (kh << 7) + lane;
        br[0]  = -C2 * s[0][r];
        br[64] = -C2 * s[1][r];
    }
}

// ---------------- softmax + PV kernel ----------------
// 256 blocks x 512 thr (8 waves x 4 rows), 160 KB LDS. V[b] staged via
// global_load_lds (latency hidden under softmax); no-max softmax (scores
// bounded, r23-validated); PV entirely on the LDS pipe.
__global__ __launch_bounds__(512) void pv_kernel(
    const float* __restrict__ sc_ws, const float* __restrict__ v_g,
    float* __restrict__ out)
{
    __shared__ float kbuf[32768];   // 128 KB: V[256][128]
    __shared__ float sB[8192];      //  32 KB: 8 waves x attn[4][256]

    const int tid  = threadIdx.x;
    const int lane = tid & 63;
    const int wv   = __builtin_amdgcn_readfirstlane(tid >> 6);  // 0..7

    const int xcd = blockIdx.x & 7;
    const int sub = blockIdx.x >> 3;          // 0..31
    const int b   = (xcd << 2) + (sub >> 3);  // same XCD mapping as score kernel
    const int qr0 = ((sub & 7) << 5) + (wv << 2);

    float* strip = sB + (wv << 10);

    // stage V[b] (128 KB) async: 16 x 1KB chunks per wave (zero VGPR)
    {
        const float* vb = v_g + (size_t)b * 32768;
        #pragma unroll
        for (int c = 0; c < 16; ++c) {
            int chunk = (wv << 4) + c;
            stage16(vb + (chunk << 8) + (lane << 2), kbuf + (chunk << 8));
        }
    }

    // softmax (no-max; scores already x(-C2)) — overlaps V-stage latency
    #pragma unroll
    for (int r = 0; r < 4; ++r) {
        const float* srow = sc_ws + (size_t)(b * 256 + qr0 + r) * 256;
        float4 sv = *(const float4*)(srow + (lane << 2));     // 1KB coalesced, L2-hot
        float p0 = __builtin_amdgcn_exp2f(sv.x);
        float p1 = __builtin_amdgcn_exp2f(sv.y);
        float p2 = __builtin_amdgcn_exp2f(sv.z);
        float p3 = __builtin_amdgcn_exp2f(sv.w);
        float sum = (p0 + p1) + (p2 + p3);
        #pragma unroll
        for (int off = 32; off; off >>= 1) sum += __shfl_xor(sum, off);
        float inv = __builtin_amdgcn_rcpf(sum);
        float4 at; at.x = p0 * inv; at.y = p1 * inv; at.z = p2 * inv; at.w = p3 * inv;
        *(float4*)&strip[(r << 8) + (lane << 2)] = at;        // wave-private
    }
    __syncthreads();    // drains V stage (vmcnt) + publishes kbuf

    // PV entirely on the LDS pipe: lane = h-pair (h = 2*lane, 2*lane+1)
    float2 o0, o1, o2, o3;
    o0.x = o0.y = o1.x = o1.y = 0.f;
    o2.x = o2.y = o3.x = o3.y = 0.f;
    #pragma unroll 4
    for (int j4 = 0; j4 < 64; ++j4) {
        float4 a0 = *(const float4*)(strip + (j4 << 2));      // row bcasts
        float4 a1 = *(const float4*)(strip + 256 + (j4 << 2));
        float4 a2 = *(const float4*)(strip + 512 + (j4 << 2));
        float4 a3 = *(const float4*)(strip + 768 + (j4 << 2));
        #pragma unroll
        for (int i = 0; i < 4; ++i) {
            float2 v2 = *(const float2*)&kbuf[(((j4 << 2) + i) << 7) + (lane << 1)];
            float c0 = (&a0.x)[i], c1 = (&a1.x)[i], c2 = (&a2.x)[i], c3 = (&a3.x)[i];
            o0.x = fmaf(c0, v2.x, o0.x); o0.y = fmaf(c0, v2.y, o0.y);
            o1.x = fmaf(c1, v2.x, o1.x); o1.y = fmaf(c1, v2.y, o1.y);
            o2.x = fmaf(c2, v2.x, o2.x); o2.y = fmaf(c2, v2.y, o2.y);
            o3.x = fmaf(c3, v2.x, o3.x); o3.y = fmaf(c3, v2.y, o3.y);
        }
    }

    float* ob = out + (size_t)(b * 256 + qr0) * 128 + (lane << 1);
    *(float2*)(ob)       = o0;
    *(float2*)(ob + 128) = o1;
    *(float2*)(ob + 256) = o2;
    *(float2*)(ob + 384) = o3;
}

extern "C" void kernel_launch(void* const* d_in, const int* in_sizes, int n_in,
                              void* d_out, int out_size, void* d_ws, size_t ws_size,
                              hipStream_t stream) {
    const float* q = (const float*)d_in[0];
    const float* k = (const float*)d_in[1];
    const float* v = (const float*)d_in[2];
    const float* w = (const float*)d_in[3];
    float* out = (float*)d_out;
    float* sc  = (float*)d_ws;                 // 32*256*256*4 = 8 MB
    score_kernel<<<512, 512, 0, stream>>>(q, k, w, sc);
    pv_kernel<<<256, 512, 0, stream>>>(sc, v, out);
}